// Round 17
// baseline (774.878 us; speedup 1.0000x reference)
//
#include <hip/hip_runtime.h>
#include <cmath>

// DTASNN embedding via i8 QUAD-limb MFMA implicit conv, halo-redundant pairwise
// fusion: 4 dispatches (prep_all, pair(t=0,1), pair(t=2,3), final(t=4)).
//
// Numerics (validated R12/R14, absmax 0.0): inputs binary -> exact i8; weights
// w = 2^-8*L1 + 2^-15*L2 + 2^-22*L3 + 2^-29*L4 (residual RMS ~1e-8);
// mfma_i32_16x16x64_i8 integer-exact; fp32 reconstruction small-to-large.
//
// R17 = R16 with the staging index bug fixed: `i & 767` is NOT a wrap at 768
// (768&767=512) -> spikes_{t-1} tile was scrambled for pair(t=2) (t=0 skips
// spike staging, masking the bug there). Fix: j = sp ? i-768 : i.
// R16 structure: VM/CNT in lane registers (phase-2 ownership lane-aligned with
// phase 3); LDS = U1 57024 + U2 38016 = 95040 B.
//
// ws: vmemC 8MB | outC 8MB | s1 2MB | s3 2MB | evb 10.5MB | Wp 576KB | tabs

typedef __attribute__((ext_vector_type(4))) int intx4;

#define HW 64
#define TT 5
#define PLANE 4096
#define CSTR 144                  // px stride bytes (128 ch + 16 pad): odd 9 quads
#define RSTR (66 * CSTR)          // row stride 9504 B
#define U1SZ (6 * RSTR)           // 57024 B (6-row tile for the 4-row step)
#define U2SZ (4 * RSTR)           // 38016 B (4-row tile for the 2-row step)
#define WPL 147456                // per-limb Wp bytes

// ---- merged prep: weight limbs + tables (blocks 0..35) | events->i8 (36..675) ----
__global__ __launch_bounds__(256) void prep_all(
    const float* __restrict__ w_in, const float* __restrict__ w_gate,
    const float* __restrict__ b_in, const float* __restrict__ b_gate,
    const float* __restrict__ tdec, const float* __restrict__ ev,
    signed char* __restrict__ Wp, float* __restrict__ tabs,
    signed char* __restrict__ evb)
{
  if (blockIdx.x < 36) {
    const int idx = blockIdx.x * 256 + threadIdx.x;
    // Wp[limb]: addr = ((tap*2+ks)*4 + q)*2048 + o*16 + j ; o=g*16+i,
    // i<8 -> cur row co=g*8+i, i>=8 -> gate row 64+co; c = ks*64+q*16+j.
    {
      const int o   = idx & 127;
      const int q   = (idx >> 7) & 3;
      const int ks  = (idx >> 9) & 1;
      const int tap = idx >> 10;             // 0..8
      const int g = o >> 4, i = o & 15;
      const int row = (i >> 3) * 64 + g * 8 + (i & 7);
      int p1[4], p2[4], p3[4], p4[4];
#pragma unroll
      for (int wd = 0; wd < 4; ++wd) {
        int v1 = 0, v2 = 0, v3 = 0, v4 = 0;
#pragma unroll
        for (int jb = 0; jb < 4; ++jb) {
          const int j = wd * 4 + jb;
          const int c = ks * 64 + q * 16 + j;
          const float w = (c < 64) ? w_in[(row * 64 + c) * 9 + tap]
                                   : w_gate[(row * 64 + (c - 64)) * 9 + tap];
          float a1 = fminf(fmaxf(rintf(w * 256.f), -127.f), 127.f);
          float r1 = w * 256.f - a1;
          float a2 = rintf(r1 * 128.f);
          float r2 = r1 * 128.f - a2;
          float a3 = rintf(r2 * 128.f);
          float r3 = r2 * 128.f - a3;
          float a4 = rintf(r3 * 128.f);
          v1 |= ((int)a1 & 255) << (8 * jb);
          v2 |= ((int)a2 & 255) << (8 * jb);
          v3 |= ((int)a3 & 255) << (8 * jb);
          v4 |= ((int)a4 & 255) << (8 * jb);
        }
        p1[wd] = v1; p2[wd] = v2; p3[wd] = v3; p4[wd] = v4;
      }
      intx4* d = (intx4*)(Wp + (size_t)idx * 16);
      d[0]                          = intx4{p1[0], p1[1], p1[2], p1[3]};
      *(intx4*)((char*)d + WPL)     = intx4{p2[0], p2[1], p2[2], p2[3]};
      *(intx4*)((char*)d + 2 * WPL) = intx4{p3[0], p3[1], p3[2], p3[3]};
      *(intx4*)((char*)d + 3 * WPL) = intx4{p4[0], p4[1], p4[2], p4[3]};
    }
    if (idx < 448) {                         // tabs: bc|bg [128], th [5][64]
      if (idx < 128) tabs[idx] = b_in[idx] + b_gate[idx];
      else {
        const int t = (idx - 128) >> 6, co = (idx - 128) & 63;
        tabs[idx] = powf(tdec[co], (float)t);  // THRESH=1.0
      }
    }
  } else {
    const int row = (blockIdx.x - 36) * 4 + (threadIdx.x >> 6);  // (b,tp,h)
    const int w   = threadIdx.x & 63;
    const int b  = row / (TT * HW);
    const int rm = row % (TT * HW);
    const int tp = rm / HW;
    const int h  = rm % HW;
    const float* src = ev + ((size_t)(b * TT + tp) * 64) * PLANE + h * HW + w;
    signed char* dst = evb + ((size_t)((b * TT + tp) * PLANE + h * HW + w)) * 64;
#pragma unroll
    for (int k = 0; k < 8; ++k) {
      unsigned long long pk = 0;
#pragma unroll
      for (int j = 0; j < 8; ++j)
        pk |= (src[(size_t)(k * 8 + j) * PLANE] != 0.f) ? (1ull << (8 * j)) : 0ull;
      *(unsigned long long*)(dst + k * 8) = pk;
    }
  }
}

// K=128 implicit-conv MFMA over one output row (4 px-tiles, 9 taps, 4 limbs)
__device__ __forceinline__ void conv128(const signed char* __restrict__ Ub, int lr,
    int laneB, const signed char* __restrict__ wlane,
    intx4* __restrict__ a1, intx4* __restrict__ a2,
    intx4* __restrict__ a3, intx4* __restrict__ a4)
{
  for (int tap = 0; tap < 9; ++tap) {
    const int kh = (tap * 11) >> 5;          // tap/3
    const int kw = tap - 3 * kh;
#pragma unroll
    for (int ks = 0; ks < 2; ++ks) {
      const signed char* wp = wlane + (tap * 2 + ks) * 8192;
      const intx4 A1 = *(const intx4*)(wp);
      const intx4 A2 = *(const intx4*)(wp + WPL);
      const intx4 A3 = *(const intx4*)(wp + 2 * WPL);
      const intx4 A4 = *(const intx4*)(wp + 3 * WPL);
      const signed char* ub = Ub + (lr - 1 + kh) * RSTR + kw * CSTR + ks * 64 + laneB;
#pragma unroll
      for (int tt = 0; tt < 4; ++tt) {
        const intx4 B = *(const intx4*)(ub + tt * (16 * CSTR));
        a1[tt] = __builtin_amdgcn_mfma_i32_16x16x64_i8(A1, B, a1[tt], 0, 0, 0);
        a2[tt] = __builtin_amdgcn_mfma_i32_16x16x64_i8(A2, B, a2[tt], 0, 0, 0);
        a3[tt] = __builtin_amdgcn_mfma_i32_16x16x64_i8(A3, B, a3[tt], 0, 0, 0);
        a4[tt] = __builtin_amdgcn_mfma_i32_16x16x64_i8(A4, B, a4[tt], 0, 0, 0);
      }
    }
  }
}

__device__ __forceinline__ float recon(int a1, int a2, int a3, int a4) {
  return fmaf((float)a1, 0x1p-8f, fmaf((float)a2, 0x1p-15f,
         fmaf((float)a3, 0x1p-22f, (float)a4 * 0x1p-29f)));
}

// ---- fused pair: steps t and t+1 (t in {0,2}) ----
__global__ __launch_bounds__(1024, 4) void snn_pair(
    const signed char* __restrict__ evb,
    const signed char* __restrict__ Wp,
    const float*       __restrict__ tabs,
    float*             __restrict__ vmemC,   // [b][h][w][c] fp32; R: v_{t-1}, W: v_{t+1}
    float*             __restrict__ outC,    // [b][h][w][c] fp32 spike counts
    const signed char* __restrict__ s_src,   // spikes_{t-1} (t=0: unused)
    signed char*       __restrict__ s_dst,   // spikes_{t+1}
    int t)
{
  __shared__ signed char U1[U1SZ];           // step-t input: rows r0-2..r0+3
  __shared__ signed char U2[U2SZ];           // step-t+1 input: rows r0-1..r0+2

  const int tid = threadIdx.x;
  const int b   = blockIdx.x >> 5;
  const int r0  = (blockIdx.x & 31) * 2;

  const int lane = tid & 63;
  const int g    = (tid >> 6) & 7;
  const int hf   = tid >> 9;
  const int ln   = lane & 15;
  const int q    = lane >> 4;

  // ---- zero LDS tiles ----
  for (int i = tid; i < U1SZ / 16; i += 1024) ((intx4*)U1)[i] = intx4{0,0,0,0};
  for (int i = tid; i < U2SZ / 16; i += 1024) ((intx4*)U2)[i] = intx4{0,0,0,0};
  __syncthreads();

  // ---- stage: U1 events_t + spikes_{t-1} (6 rows), U2 events_{t+1} (4 rows) ----
  // items: [0,768) U1 events, [768,1536) U1 spikes, [1536,2048) U2 events
  const int pe1 = TT - 1 - t, pe2 = TT - 2 - t;
  for (int i = tid; i < 2048; i += 1024) {
    if (i < 1536) {
      const bool sp = (i >= 768);
      const int  j  = sp ? (i - 768) : i;    // R17 FIX: was `i & 767` (wrong wrap)
      const int half = j & 1;
      const int px   = j >> 1;               // 0..383
      const int lr   = px >> 6;
      const int col  = px & 63;
      const int row  = r0 - 2 + lr;
      if (row >= 0 && row < HW && (!sp || t > 0)) {
        const signed char* src = sp
          ? s_src + ((size_t)((b * HW + row) * HW + col)) * 64 + half * 32
          : evb + ((size_t)((b * TT + pe1) * PLANE + row * HW + col)) * 64 + half * 32;
        signed char* dst = U1 + (lr * 66 + col + 1) * CSTR + (sp ? 64 : 0) + half * 32;
        *(intx4*)dst        = *(const intx4*)src;
        *(intx4*)(dst + 16) = *(const intx4*)(src + 16);
      }
    } else {
      const int j = i - 1536;
      const int half = j & 1;
      const int px   = j >> 1;               // 0..255
      const int lr   = px >> 6;
      const int col  = px & 63;
      const int row  = r0 - 1 + lr;
      if (row >= 0 && row < HW) {
        const signed char* src =
          evb + ((size_t)((b * TT + pe2) * PLANE + row * HW + col)) * 64 + half * 32;
        signed char* dst = U2 + (lr * 66 + col + 1) * CSTR + half * 32;
        *(intx4*)dst        = *(const intx4*)src;
        *(intx4*)(dst + 16) = *(const intx4*)(src + 16);
      }
    }
  }
  __syncthreads();

  const int laneB = ln * CSTR + q * 16;
  const signed char* wlane = Wp + q * 2048 + (g * 16 + ln) * 16;
  const int co0 = g * 8 + (q & 1) * 4;
  float bc[4], bg[4];
#pragma unroll
  for (int r = 0; r < 4; ++r) { bc[r] = tabs[co0 + r]; bg[r] = tabs[64 + co0 + r]; }

  // lane-carried state for the OWNED row (r0 + 1 - hf), consumed in phase 3
  float vmreg[4][4];                         // vmem_t per (tt, r)
  uint  cnt_t[4];                            // step-t fired per tt (byte per r)

  // ---- phase 2: step t on 4 rows; wave (g,hf) owns rr = r0+1-hf (hr = 1) ----
#pragma unroll 1
  for (int hr = 0; hr < 2; ++hr) {
    // hr=0: halo row (hf=0 -> r0-1, hf=1 -> r0+2); hr=1: owned row r0+1-hf
    const int rr = hr ? (r0 + 1 - hf) : (hf ? r0 + 2 : r0 - 1);
    const int lr = rr - (r0 - 2);            // U1 row index
    intx4 a1[4], a2[4], a3[4], a4[4];
#pragma unroll
    for (int tt = 0; tt < 4; ++tt) {
      a1[tt] = intx4{0,0,0,0}; a2[tt] = intx4{0,0,0,0};
      a3[tt] = intx4{0,0,0,0}; a4[tt] = intx4{0,0,0,0};
    }
    conv128(U1, lr, laneB, wlane, a1, a2, a3, a4);

    const bool inr = (rr >= 0) && (rr < HW); // owned rows always in range
    const int lr2 = rr - (r0 - 1);           // U2 row (valid when inr)
#pragma unroll
    for (int tt = 0; tt < 4; ++tt) {
      const int col = tt * 16 + ln;
      float mine[4], other[4];
#pragma unroll
      for (int r = 0; r < 4; ++r)
        mine[r] = recon(a1[tt][r], a2[tt][r], a3[tt][r], a4[tt][r]);
#pragma unroll
      for (int r = 0; r < 4; ++r) other[r] = __shfl_xor(mine[r], 32, 64);
      if (q < 2 && inr) {
        float4 vm4 = float4{0.f, 0.f, 0.f, 0.f};
        if (t > 0)
          vm4 = *(const float4*)&vmemC[((size_t)((b * HW + rr) * HW + col)) * 64 + co0];
        uint fm = 0;
#pragma unroll
        for (int r = 0; r < 4; ++r) {
          const float cur  = mine[r] + bc[r];
          const float gp   = other[r] + bg[r];
          const float gate = 1.f / (1.f + expf(-gp));
          const float v    = gate * (&vm4.x)[r] + cur;   // vmem = gate*vmem + cur
          const bool fired = (v >= tabs[128 + t * 64 + co0 + r]);
          (&vm4.x)[r] = fired ? 0.f : v;                 // hard reset to VRESET=0
          fm |= fired ? (1u << (8 * r)) : 0u;
        }
        if (hr) {                            // owned: keep in lane registers
#pragma unroll
          for (int r = 0; r < 4; ++r) vmreg[tt][r] = (&vm4.x)[r];
          cnt_t[tt] = fm;
        }
        *(uint*)(U2 + (lr2 * 66 + col + 1) * CSTR + 64 + co0) = fm;  // spikes_t
      }
    }
  }
  __syncthreads();                           // U2 spike tile complete

  // ---- phase 3: step t+1 on the SAME owned row rr = r0+1-hf ----
  {
    const int rr = r0 + 1 - hf;
    const int lr = 2 - hf;                   // U2 row index of rr
    intx4 a1[4], a2[4], a3[4], a4[4];
#pragma unroll
    for (int tt = 0; tt < 4; ++tt) {
      a1[tt] = intx4{0,0,0,0}; a2[tt] = intx4{0,0,0,0};
      a3[tt] = intx4{0,0,0,0}; a4[tt] = intx4{0,0,0,0};
    }
    conv128(U2, lr, laneB, wlane, a1, a2, a3, a4);
#pragma unroll
    for (int tt = 0; tt < 4; ++tt) {
      const int col = tt * 16 + ln;
      float mine[4], other[4];
#pragma unroll
      for (int r = 0; r < 4; ++r)
        mine[r] = recon(a1[tt][r], a2[tt][r], a3[tt][r], a4[tt][r]);
#pragma unroll
      for (int r = 0; r < 4; ++r) other[r] = __shfl_xor(mine[r], 32, 64);
      if (q < 2) {
        float4 vm4; float4 c4;
        uint fm = 0;
#pragma unroll
        for (int r = 0; r < 4; ++r) {
          const float cur  = mine[r] + bc[r];
          const float gp   = other[r] + bg[r];
          const float gate = 1.f / (1.f + expf(-gp));
          const float v    = gate * vmreg[tt][r] + cur;
          const bool fired = (v >= tabs[128 + (t + 1) * 64 + co0 + r]);
          (&vm4.x)[r] = fired ? 0.f : v;
          fm |= fired ? (1u << (8 * r)) : 0u;
          (&c4.x)[r] = (float)((cnt_t[tt] >> (8 * r)) & 255u)
                     + (fired ? 1.f : 0.f);  // counts of steps t and t+1
        }
        const size_t o = ((size_t)((b * HW + rr) * HW + col)) * 64 + co0;
        *(float4*)&vmemC[o] = vm4;           // vmem_{t+1}
        *(uint*)&s_dst[o]   = fm;            // spikes_{t+1}
        if (t == 0) {                        // outC poisoned -> overwrite at t=0
          *(float4*)&outC[o] = c4;
        } else {
          const float4 p = *(const float4*)&outC[o];
          *(float4*)&outC[o] = float4{p.x + c4.x, p.y + c4.y, p.z + c4.z, p.w + c4.w};
        }
      }
    }
  }
}

// ---- final step t=4: no state writes, scatter mean to d_out ----
__global__ __launch_bounds__(1024, 4) void snn_final(
    const signed char* __restrict__ evb,
    const signed char* __restrict__ Wp,
    const float*       __restrict__ tabs,
    const float*       __restrict__ vmemC,   // vmem_3
    const float*       __restrict__ outC,    // counts t=0..3
    const signed char* __restrict__ s_src,   // spikes_3
    float*             __restrict__ outF)    // d_out [b][co][h][w]
{
  __shared__ signed char U[U2SZ];            // 4 rows

  const int tid = threadIdx.x;
  const int b   = blockIdx.x >> 5;
  const int r0  = (blockIdx.x & 31) * 2;

  const int lane = tid & 63;
  const int g    = (tid >> 6) & 7;
  const int hf   = tid >> 9;
  const int ln   = lane & 15;
  const int q    = lane >> 4;

  // stage: 4 rows x 64 cols x 4 chunks (events pe=0 | spikes_3)
  const int srow = tid >> 8;
  const int scol = (tid >> 2) & 63;
  const int sch  = tid & 3;
  const int sr   = r0 + srow - 1;
  const bool svalid = (sr >= 0) && (sr < HW);
  intx4 st0 = intx4{0,0,0,0}, st1 = intx4{0,0,0,0};
  if (svalid) {
    const signed char* gs = (sch < 2)
      ? evb + ((size_t)((b * TT + 0) * PLANE + sr * HW + scol)) * 64 + sch * 32
      : s_src + ((size_t)((b * HW + sr) * HW + scol)) * 64 + (sch - 2) * 32;
    st0 = *(const intx4*)gs; st1 = *(const intx4*)(gs + 16);
  }
  for (int i = tid; i < U2SZ / 16; i += 1024) ((intx4*)U)[i] = intx4{0,0,0,0};
  __syncthreads();
  if (svalid) {
    signed char* du = U + (srow * 66 + scol + 1) * CSTR + sch * 32;
    *(intx4*)du = st0; *(intx4*)(du + 16) = st1;
  }
  __syncthreads();

  const int laneB = ln * CSTR + q * 16;
  const signed char* wlane = Wp + q * 2048 + (g * 16 + ln) * 16;
  intx4 a1[4], a2[4], a3[4], a4[4];
#pragma unroll
  for (int tt = 0; tt < 4; ++tt) {
    a1[tt] = intx4{0,0,0,0}; a2[tt] = intx4{0,0,0,0};
    a3[tt] = intx4{0,0,0,0}; a4[tt] = intx4{0,0,0,0};
  }
  conv128(U, 1 + hf, laneB, wlane, a1, a2, a3, a4);

  const int co0 = g * 8 + (q & 1) * 4;
  float bc[4], bg[4], th[4];
#pragma unroll
  for (int r = 0; r < 4; ++r) {
    bc[r] = tabs[co0 + r];
    bg[r] = tabs[64 + co0 + r];
    th[r] = tabs[128 + 4 * 64 + co0 + r];
  }
  const int hh = r0 + hf;
#pragma unroll
  for (int tt = 0; tt < 4; ++tt) {
    const int col = tt * 16 + ln;
    float mine[4], other[4];
#pragma unroll
    for (int r = 0; r < 4; ++r)
      mine[r] = recon(a1[tt][r], a2[tt][r], a3[tt][r], a4[tt][r]);
#pragma unroll
    for (int r = 0; r < 4; ++r) other[r] = __shfl_xor(mine[r], 32, 64);
    if (q < 2) {
      const size_t o = ((size_t)((b * HW + hh) * HW + col)) * 64 + co0;
      const float4 vm4 = *(const float4*)&vmemC[o];
      const float4 oc4 = *(const float4*)&outC[o];
#pragma unroll
      for (int r = 0; r < 4; ++r) {
        const float cur  = mine[r] + bc[r];
        const float gp   = other[r] + bg[r];
        const float gate = 1.f / (1.f + expf(-gp));
        const float v    = gate * (&vm4.x)[r] + cur;
        const bool fired = (v >= th[r]);
        outF[((size_t)((b * 64 + co0 + r) * HW + hh)) * HW + col]
            = ((&oc4.x)[r] + (fired ? 1.f : 0.f)) * 0.2f;   // mean over T=5
      }
    }
  }
}

extern "C" void kernel_launch(void* const* d_in, const int* in_sizes, int n_in,
                              void* d_out, int out_size, void* d_ws, size_t ws_size,
                              hipStream_t stream) {
  const float* events = (const float*)d_in[0];
  const float* w_in   = (const float*)d_in[1];
  const float* b_in   = (const float*)d_in[2];
  const float* w_gate = (const float*)d_in[3];
  const float* b_gate = (const float*)d_in[4];
  const float* tdec   = (const float*)d_in[5];
  float* out = (float*)d_out;

  char* base = (char*)d_ws;
  float*       vmemC = (float*)base;                    //  8,388,608 B
  float*       outC  = (float*)(base + 8388608);        //  8,388,608 B
  signed char* s1    = (signed char*)(base + 16777216); //  2,097,152 B (spikes_1)
  signed char* s3    = (signed char*)(base + 18874368); //  2,097,152 B (spikes_3)
  signed char* evb   = (signed char*)(base + 20971520); // 10,485,760 B
  signed char* Wp    = (signed char*)(base + 31457280); //    589,824 B
  float*       tabs  = (float*)(base + 32047104);       //      1,792 B

  hipLaunchKernelGGL(prep_all, dim3(676), dim3(256), 0, stream,
                     w_in, w_gate, b_in, b_gate, tdec, events, Wp, tabs, evb);

  hipLaunchKernelGGL(snn_pair, dim3(256), dim3(1024), 0, stream,
                     evb, Wp, tabs, vmemC, outC, s1 /*unused*/, s1, 0);
  hipLaunchKernelGGL(snn_pair, dim3(256), dim3(1024), 0, stream,
                     evb, Wp, tabs, vmemC, outC, s1, s3, 2);
  hipLaunchKernelGGL(snn_final, dim3(256), dim3(1024), 0, stream,
                     evb, Wp, tabs, vmemC, outC, s3, out);
}

// Round 18
// 770.690 us; speedup vs baseline: 1.0054x; 1.0054x over previous
//
#include <hip/hip_runtime.h>
#include <cmath>

// DTASNN embedding via i8 QUAD-limb MFMA implicit conv, halo-redundant pairwise
// fusion: 4 dispatches (prep_all, pair(t=0,1), pair(t=2,3), final(t=4)).
//
// Numerics (validated R12/R14/R17, absmax 0.0): inputs binary -> exact i8;
// weights w = 2^-8*L1 + 2^-15*L2 + 2^-22*L3 + 2^-29*L4 (residual RMS ~1e-8);
// mfma_i32_16x16x64_i8 integer-exact; fp32 reconstruction small-to-large.
//
// R18 = R17 with the register cap lifted: __launch_bounds__(1024,4) capped the
// unified VGPR+AGPR file at 128/wave; pair's vmreg+cnt live across phase-3
// conv128 pushed past it -> acc arrays spilled in the tap loop -> 950 MB scratch
// traffic/pair = 344us each. (1024,2) allows ~256 regs; the 16-wave block still
// runs 4 waves/SIMD (4 x ~200 = 800 < 2048 VGPRs/SIMD), so occupancy unchanged.
//
// ws: vmemC 8MB | outC 8MB | s1 2MB | s3 2MB | evb 10.5MB | Wp 576KB | tabs

typedef __attribute__((ext_vector_type(4))) int intx4;

#define HW 64
#define TT 5
#define PLANE 4096
#define CSTR 144                  // px stride bytes (128 ch + 16 pad): odd 9 quads
#define RSTR (66 * CSTR)          // row stride 9504 B
#define U1SZ (6 * RSTR)           // 57024 B (6-row tile for the 4-row step)
#define U2SZ (4 * RSTR)           // 38016 B (4-row tile for the 2-row step)
#define WPL 147456                // per-limb Wp bytes

// ---- merged prep: weight limbs + tables (blocks 0..35) | events->i8 (36..675) ----
__global__ __launch_bounds__(256) void prep_all(
    const float* __restrict__ w_in, const float* __restrict__ w_gate,
    const float* __restrict__ b_in, const float* __restrict__ b_gate,
    const float* __restrict__ tdec, const float* __restrict__ ev,
    signed char* __restrict__ Wp, float* __restrict__ tabs,
    signed char* __restrict__ evb)
{
  if (blockIdx.x < 36) {
    const int idx = blockIdx.x * 256 + threadIdx.x;
    // Wp[limb]: addr = ((tap*2+ks)*4 + q)*2048 + o*16 + j ; o=g*16+i,
    // i<8 -> cur row co=g*8+i, i>=8 -> gate row 64+co; c = ks*64+q*16+j.
    {
      const int o   = idx & 127;
      const int q   = (idx >> 7) & 3;
      const int ks  = (idx >> 9) & 1;
      const int tap = idx >> 10;             // 0..8
      const int g = o >> 4, i = o & 15;
      const int row = (i >> 3) * 64 + g * 8 + (i & 7);
      int p1[4], p2[4], p3[4], p4[4];
#pragma unroll
      for (int wd = 0; wd < 4; ++wd) {
        int v1 = 0, v2 = 0, v3 = 0, v4 = 0;
#pragma unroll
        for (int jb = 0; jb < 4; ++jb) {
          const int j = wd * 4 + jb;
          const int c = ks * 64 + q * 16 + j;
          const float w = (c < 64) ? w_in[(row * 64 + c) * 9 + tap]
                                   : w_gate[(row * 64 + (c - 64)) * 9 + tap];
          float a1 = fminf(fmaxf(rintf(w * 256.f), -127.f), 127.f);
          float r1 = w * 256.f - a1;
          float a2 = rintf(r1 * 128.f);
          float r2 = r1 * 128.f - a2;
          float a3 = rintf(r2 * 128.f);
          float r3 = r2 * 128.f - a3;
          float a4 = rintf(r3 * 128.f);
          v1 |= ((int)a1 & 255) << (8 * jb);
          v2 |= ((int)a2 & 255) << (8 * jb);
          v3 |= ((int)a3 & 255) << (8 * jb);
          v4 |= ((int)a4 & 255) << (8 * jb);
        }
        p1[wd] = v1; p2[wd] = v2; p3[wd] = v3; p4[wd] = v4;
      }
      intx4* d = (intx4*)(Wp + (size_t)idx * 16);
      d[0]                          = intx4{p1[0], p1[1], p1[2], p1[3]};
      *(intx4*)((char*)d + WPL)     = intx4{p2[0], p2[1], p2[2], p2[3]};
      *(intx4*)((char*)d + 2 * WPL) = intx4{p3[0], p3[1], p3[2], p3[3]};
      *(intx4*)((char*)d + 3 * WPL) = intx4{p4[0], p4[1], p4[2], p4[3]};
    }
    if (idx < 448) {                         // tabs: bc|bg [128], th [5][64]
      if (idx < 128) tabs[idx] = b_in[idx] + b_gate[idx];
      else {
        const int t = (idx - 128) >> 6, co = (idx - 128) & 63;
        tabs[idx] = powf(tdec[co], (float)t);  // THRESH=1.0
      }
    }
  } else {
    const int row = (blockIdx.x - 36) * 4 + (threadIdx.x >> 6);  // (b,tp,h)
    const int w   = threadIdx.x & 63;
    const int b  = row / (TT * HW);
    const int rm = row % (TT * HW);
    const int tp = rm / HW;
    const int h  = rm % HW;
    const float* src = ev + ((size_t)(b * TT + tp) * 64) * PLANE + h * HW + w;
    signed char* dst = evb + ((size_t)((b * TT + tp) * PLANE + h * HW + w)) * 64;
#pragma unroll
    for (int k = 0; k < 8; ++k) {
      unsigned long long pk = 0;
#pragma unroll
      for (int j = 0; j < 8; ++j)
        pk |= (src[(size_t)(k * 8 + j) * PLANE] != 0.f) ? (1ull << (8 * j)) : 0ull;
      *(unsigned long long*)(dst + k * 8) = pk;
    }
  }
}

// K=128 implicit-conv MFMA over one output row (4 px-tiles, 9 taps, 4 limbs)
__device__ __forceinline__ void conv128(const signed char* __restrict__ Ub, int lr,
    int laneB, const signed char* __restrict__ wlane,
    intx4* __restrict__ a1, intx4* __restrict__ a2,
    intx4* __restrict__ a3, intx4* __restrict__ a4)
{
  for (int tap = 0; tap < 9; ++tap) {
    const int kh = (tap * 11) >> 5;          // tap/3
    const int kw = tap - 3 * kh;
#pragma unroll
    for (int ks = 0; ks < 2; ++ks) {
      const signed char* wp = wlane + (tap * 2 + ks) * 8192;
      const intx4 A1 = *(const intx4*)(wp);
      const intx4 A2 = *(const intx4*)(wp + WPL);
      const intx4 A3 = *(const intx4*)(wp + 2 * WPL);
      const intx4 A4 = *(const intx4*)(wp + 3 * WPL);
      const signed char* ub = Ub + (lr - 1 + kh) * RSTR + kw * CSTR + ks * 64 + laneB;
#pragma unroll
      for (int tt = 0; tt < 4; ++tt) {
        const intx4 B = *(const intx4*)(ub + tt * (16 * CSTR));
        a1[tt] = __builtin_amdgcn_mfma_i32_16x16x64_i8(A1, B, a1[tt], 0, 0, 0);
        a2[tt] = __builtin_amdgcn_mfma_i32_16x16x64_i8(A2, B, a2[tt], 0, 0, 0);
        a3[tt] = __builtin_amdgcn_mfma_i32_16x16x64_i8(A3, B, a3[tt], 0, 0, 0);
        a4[tt] = __builtin_amdgcn_mfma_i32_16x16x64_i8(A4, B, a4[tt], 0, 0, 0);
      }
    }
  }
}

__device__ __forceinline__ float recon(int a1, int a2, int a3, int a4) {
  return fmaf((float)a1, 0x1p-8f, fmaf((float)a2, 0x1p-15f,
         fmaf((float)a3, 0x1p-22f, (float)a4 * 0x1p-29f)));
}

// ---- fused pair: steps t and t+1 (t in {0,2}) ----
__global__ __launch_bounds__(1024, 2) void snn_pair(
    const signed char* __restrict__ evb,
    const signed char* __restrict__ Wp,
    const float*       __restrict__ tabs,
    float*             __restrict__ vmemC,   // [b][h][w][c] fp32; R: v_{t-1}, W: v_{t+1}
    float*             __restrict__ outC,    // [b][h][w][c] fp32 spike counts
    const signed char* __restrict__ s_src,   // spikes_{t-1} (t=0: unused)
    signed char*       __restrict__ s_dst,   // spikes_{t+1}
    int t)
{
  __shared__ signed char U1[U1SZ];           // step-t input: rows r0-2..r0+3
  __shared__ signed char U2[U2SZ];           // step-t+1 input: rows r0-1..r0+2

  const int tid = threadIdx.x;
  const int b   = blockIdx.x >> 5;
  const int r0  = (blockIdx.x & 31) * 2;

  const int lane = tid & 63;
  const int g    = (tid >> 6) & 7;
  const int hf   = tid >> 9;
  const int ln   = lane & 15;
  const int q    = lane >> 4;

  // ---- zero LDS tiles ----
  for (int i = tid; i < U1SZ / 16; i += 1024) ((intx4*)U1)[i] = intx4{0,0,0,0};
  for (int i = tid; i < U2SZ / 16; i += 1024) ((intx4*)U2)[i] = intx4{0,0,0,0};
  __syncthreads();

  // ---- stage: U1 events_t + spikes_{t-1} (6 rows), U2 events_{t+1} (4 rows) ----
  // items: [0,768) U1 events, [768,1536) U1 spikes, [1536,2048) U2 events
  const int pe1 = TT - 1 - t, pe2 = TT - 2 - t;
  for (int i = tid; i < 2048; i += 1024) {
    if (i < 1536) {
      const bool sp = (i >= 768);
      const int  j  = sp ? (i - 768) : i;    // R17 fix: exact wrap at 768
      const int half = j & 1;
      const int px   = j >> 1;               // 0..383
      const int lr   = px >> 6;
      const int col  = px & 63;
      const int row  = r0 - 2 + lr;
      if (row >= 0 && row < HW && (!sp || t > 0)) {
        const signed char* src = sp
          ? s_src + ((size_t)((b * HW + row) * HW + col)) * 64 + half * 32
          : evb + ((size_t)((b * TT + pe1) * PLANE + row * HW + col)) * 64 + half * 32;
        signed char* dst = U1 + (lr * 66 + col + 1) * CSTR + (sp ? 64 : 0) + half * 32;
        *(intx4*)dst        = *(const intx4*)src;
        *(intx4*)(dst + 16) = *(const intx4*)(src + 16);
      }
    } else {
      const int j = i - 1536;
      const int half = j & 1;
      const int px   = j >> 1;               // 0..255
      const int lr   = px >> 6;
      const int col  = px & 63;
      const int row  = r0 - 1 + lr;
      if (row >= 0 && row < HW) {
        const signed char* src =
          evb + ((size_t)((b * TT + pe2) * PLANE + row * HW + col)) * 64 + half * 32;
        signed char* dst = U2 + (lr * 66 + col + 1) * CSTR + half * 32;
        *(intx4*)dst        = *(const intx4*)src;
        *(intx4*)(dst + 16) = *(const intx4*)(src + 16);
      }
    }
  }
  __syncthreads();

  const int laneB = ln * CSTR + q * 16;
  const signed char* wlane = Wp + q * 2048 + (g * 16 + ln) * 16;
  const int co0 = g * 8 + (q & 1) * 4;
  float bc[4], bg[4];
#pragma unroll
  for (int r = 0; r < 4; ++r) { bc[r] = tabs[co0 + r]; bg[r] = tabs[64 + co0 + r]; }

  // lane-carried state for the OWNED row (r0 + 1 - hf), consumed in phase 3
  float vmreg[4][4];                         // vmem_t per (tt, r)
  uint  cnt_t[4];                            // step-t fired per tt (byte per r)

  // ---- phase 2: step t on 4 rows; wave (g,hf) owns rr = r0+1-hf (hr = 1) ----
#pragma unroll 1
  for (int hr = 0; hr < 2; ++hr) {
    // hr=0: halo row (hf=0 -> r0-1, hf=1 -> r0+2); hr=1: owned row r0+1-hf
    const int rr = hr ? (r0 + 1 - hf) : (hf ? r0 + 2 : r0 - 1);
    const int lr = rr - (r0 - 2);            // U1 row index
    intx4 a1[4], a2[4], a3[4], a4[4];
#pragma unroll
    for (int tt = 0; tt < 4; ++tt) {
      a1[tt] = intx4{0,0,0,0}; a2[tt] = intx4{0,0,0,0};
      a3[tt] = intx4{0,0,0,0}; a4[tt] = intx4{0,0,0,0};
    }
    conv128(U1, lr, laneB, wlane, a1, a2, a3, a4);

    const bool inr = (rr >= 0) && (rr < HW); // owned rows always in range
    const int lr2 = rr - (r0 - 1);           // U2 row (valid when inr)
#pragma unroll
    for (int tt = 0; tt < 4; ++tt) {
      const int col = tt * 16 + ln;
      float mine[4], other[4];
#pragma unroll
      for (int r = 0; r < 4; ++r)
        mine[r] = recon(a1[tt][r], a2[tt][r], a3[tt][r], a4[tt][r]);
#pragma unroll
      for (int r = 0; r < 4; ++r) other[r] = __shfl_xor(mine[r], 32, 64);
      if (q < 2 && inr) {
        float4 vm4 = float4{0.f, 0.f, 0.f, 0.f};
        if (t > 0)
          vm4 = *(const float4*)&vmemC[((size_t)((b * HW + rr) * HW + col)) * 64 + co0];
        uint fm = 0;
#pragma unroll
        for (int r = 0; r < 4; ++r) {
          const float cur  = mine[r] + bc[r];
          const float gp   = other[r] + bg[r];
          const float gate = 1.f / (1.f + expf(-gp));
          const float v    = gate * (&vm4.x)[r] + cur;   // vmem = gate*vmem + cur
          const bool fired = (v >= tabs[128 + t * 64 + co0 + r]);
          (&vm4.x)[r] = fired ? 0.f : v;                 // hard reset to VRESET=0
          fm |= fired ? (1u << (8 * r)) : 0u;
        }
        if (hr) {                            // owned: keep in lane registers
#pragma unroll
          for (int r = 0; r < 4; ++r) vmreg[tt][r] = (&vm4.x)[r];
          cnt_t[tt] = fm;
        }
        *(uint*)(U2 + (lr2 * 66 + col + 1) * CSTR + 64 + co0) = fm;  // spikes_t
      }
    }
  }
  __syncthreads();                           // U2 spike tile complete

  // ---- phase 3: step t+1 on the SAME owned row rr = r0+1-hf ----
  {
    const int rr = r0 + 1 - hf;
    const int lr = 2 - hf;                   // U2 row index of rr
    intx4 a1[4], a2[4], a3[4], a4[4];
#pragma unroll
    for (int tt = 0; tt < 4; ++tt) {
      a1[tt] = intx4{0,0,0,0}; a2[tt] = intx4{0,0,0,0};
      a3[tt] = intx4{0,0,0,0}; a4[tt] = intx4{0,0,0,0};
    }
    conv128(U2, lr, laneB, wlane, a1, a2, a3, a4);
#pragma unroll
    for (int tt = 0; tt < 4; ++tt) {
      const int col = tt * 16 + ln;
      float mine[4], other[4];
#pragma unroll
      for (int r = 0; r < 4; ++r)
        mine[r] = recon(a1[tt][r], a2[tt][r], a3[tt][r], a4[tt][r]);
#pragma unroll
      for (int r = 0; r < 4; ++r) other[r] = __shfl_xor(mine[r], 32, 64);
      if (q < 2) {
        float4 vm4; float4 c4;
        uint fm = 0;
#pragma unroll
        for (int r = 0; r < 4; ++r) {
          const float cur  = mine[r] + bc[r];
          const float gp   = other[r] + bg[r];
          const float gate = 1.f / (1.f + expf(-gp));
          const float v    = gate * vmreg[tt][r] + cur;
          const bool fired = (v >= tabs[128 + (t + 1) * 64 + co0 + r]);
          (&vm4.x)[r] = fired ? 0.f : v;
          fm |= fired ? (1u << (8 * r)) : 0u;
          (&c4.x)[r] = (float)((cnt_t[tt] >> (8 * r)) & 255u)
                     + (fired ? 1.f : 0.f);  // counts of steps t and t+1
        }
        const size_t o = ((size_t)((b * HW + rr) * HW + col)) * 64 + co0;
        *(float4*)&vmemC[o] = vm4;           // vmem_{t+1}
        *(uint*)&s_dst[o]   = fm;            // spikes_{t+1}
        if (t == 0) {                        // outC poisoned -> overwrite at t=0
          *(float4*)&outC[o] = c4;
        } else {
          const float4 p = *(const float4*)&outC[o];
          *(float4*)&outC[o] = float4{p.x + c4.x, p.y + c4.y, p.z + c4.z, p.w + c4.w};
        }
      }
    }
  }
}

// ---- final step t=4: no state writes, scatter mean to d_out ----
__global__ __launch_bounds__(1024, 2) void snn_final(
    const signed char* __restrict__ evb,
    const signed char* __restrict__ Wp,
    const float*       __restrict__ tabs,
    const float*       __restrict__ vmemC,   // vmem_3
    const float*       __restrict__ outC,    // counts t=0..3
    const signed char* __restrict__ s_src,   // spikes_3
    float*             __restrict__ outF)    // d_out [b][co][h][w]
{
  __shared__ signed char U[U2SZ];            // 4 rows

  const int tid = threadIdx.x;
  const int b   = blockIdx.x >> 5;
  const int r0  = (blockIdx.x & 31) * 2;

  const int lane = tid & 63;
  const int g    = (tid >> 6) & 7;
  const int hf   = tid >> 9;
  const int ln   = lane & 15;
  const int q    = lane >> 4;

  // stage: 4 rows x 64 cols x 4 chunks (events pe=0 | spikes_3)
  const int srow = tid >> 8;
  const int scol = (tid >> 2) & 63;
  const int sch  = tid & 3;
  const int sr   = r0 + srow - 1;
  const bool svalid = (sr >= 0) && (sr < HW);
  intx4 st0 = intx4{0,0,0,0}, st1 = intx4{0,0,0,0};
  if (svalid) {
    const signed char* gs = (sch < 2)
      ? evb + ((size_t)((b * TT + 0) * PLANE + sr * HW + scol)) * 64 + sch * 32
      : s_src + ((size_t)((b * HW + sr) * HW + scol)) * 64 + (sch - 2) * 32;
    st0 = *(const intx4*)gs; st1 = *(const intx4*)(gs + 16);
  }
  for (int i = tid; i < U2SZ / 16; i += 1024) ((intx4*)U)[i] = intx4{0,0,0,0};
  __syncthreads();
  if (svalid) {
    signed char* du = U + (srow * 66 + scol + 1) * CSTR + sch * 32;
    *(intx4*)du = st0; *(intx4*)(du + 16) = st1;
  }
  __syncthreads();

  const int laneB = ln * CSTR + q * 16;
  const signed char* wlane = Wp + q * 2048 + (g * 16 + ln) * 16;
  intx4 a1[4], a2[4], a3[4], a4[4];
#pragma unroll
  for (int tt = 0; tt < 4; ++tt) {
    a1[tt] = intx4{0,0,0,0}; a2[tt] = intx4{0,0,0,0};
    a3[tt] = intx4{0,0,0,0}; a4[tt] = intx4{0,0,0,0};
  }
  conv128(U, 1 + hf, laneB, wlane, a1, a2, a3, a4);

  const int co0 = g * 8 + (q & 1) * 4;
  float bc[4], bg[4], th[4];
#pragma unroll
  for (int r = 0; r < 4; ++r) {
    bc[r] = tabs[co0 + r];
    bg[r] = tabs[64 + co0 + r];
    th[r] = tabs[128 + 4 * 64 + co0 + r];
  }
  const int hh = r0 + hf;
#pragma unroll
  for (int tt = 0; tt < 4; ++tt) {
    const int col = tt * 16 + ln;
    float mine[4], other[4];
#pragma unroll
    for (int r = 0; r < 4; ++r)
      mine[r] = recon(a1[tt][r], a2[tt][r], a3[tt][r], a4[tt][r]);
#pragma unroll
    for (int r = 0; r < 4; ++r) other[r] = __shfl_xor(mine[r], 32, 64);
    if (q < 2) {
      const size_t o = ((size_t)((b * HW + hh) * HW + col)) * 64 + co0;
      const float4 vm4 = *(const float4*)&vmemC[o];
      const float4 oc4 = *(const float4*)&outC[o];
#pragma unroll
      for (int r = 0; r < 4; ++r) {
        const float cur  = mine[r] + bc[r];
        const float gp   = other[r] + bg[r];
        const float gate = 1.f / (1.f + expf(-gp));
        const float v    = gate * (&vm4.x)[r] + cur;
        const bool fired = (v >= th[r]);
        outF[((size_t)((b * 64 + co0 + r) * HW + hh)) * HW + col]
            = ((&oc4.x)[r] + (fired ? 1.f : 0.f)) * 0.2f;   // mean over T=5
      }
    }
  }
}

extern "C" void kernel_launch(void* const* d_in, const int* in_sizes, int n_in,
                              void* d_out, int out_size, void* d_ws, size_t ws_size,
                              hipStream_t stream) {
  const float* events = (const float*)d_in[0];
  const float* w_in   = (const float*)d_in[1];
  const float* b_in   = (const float*)d_in[2];
  const float* w_gate = (const float*)d_in[3];
  const float* b_gate = (const float*)d_in[4];
  const float* tdec   = (const float*)d_in[5];
  float* out = (float*)d_out;

  char* base = (char*)d_ws;
  float*       vmemC = (float*)base;                    //  8,388,608 B
  float*       outC  = (float*)(base + 8388608);        //  8,388,608 B
  signed char* s1    = (signed char*)(base + 16777216); //  2,097,152 B (spikes_1)
  signed char* s3    = (signed char*)(base + 18874368); //  2,097,152 B (spikes_3)
  signed char* evb   = (signed char*)(base + 20971520); // 10,485,760 B
  signed char* Wp    = (signed char*)(base + 31457280); //    589,824 B
  float*       tabs  = (float*)(base + 32047104);       //      1,792 B

  hipLaunchKernelGGL(prep_all, dim3(676), dim3(256), 0, stream,
                     w_in, w_gate, b_in, b_gate, tdec, events, Wp, tabs, evb);

  hipLaunchKernelGGL(snn_pair, dim3(256), dim3(1024), 0, stream,
                     evb, Wp, tabs, vmemC, outC, s1 /*unused*/, s1, 0);
  hipLaunchKernelGGL(snn_pair, dim3(256), dim3(1024), 0, stream,
                     evb, Wp, tabs, vmemC, outC, s1, s3, 2);
  hipLaunchKernelGGL(snn_final, dim3(256), dim3(1024), 0, stream,
                     evb, Wp, tabs, vmemC, outC, s3, out);
}